// Round 6
// baseline (575.410 us; speedup 1.0000x reference)
//
#include <hip/hip_runtime.h>

#define OBS 8
#define PREDL 12
#define NCELL 19   // cell evals t=0..18; emissions head(h_7..h_18)

// LDS map (bytes)
#define W_OFF     0        // 131072: W_hh all 4 gates, 512 rows x 256B bf16, swizzled
#define H_OFF     131072   // 16384: h buffer, 64 rows x 256B, swizzled
#define SCR_OFF   147456   // 4096: head partials [8 chunks][64 rows][2] f32
#define XBUF_OFF  151552   // 512: x per row [64][2] f32
#define LDS_BYTES 152064

typedef short short8 __attribute__((ext_vector_type(8)));
typedef float f32x4  __attribute__((ext_vector_type(4)));
struct U128 { unsigned a, b, c, d; };

__device__ __forceinline__ float sigm(float x) {
    return __builtin_amdgcn_rcpf(1.0f + __builtin_amdgcn_exp2f(x * -1.4426950408889634f));
}
__device__ __forceinline__ float tanh_(float x) {
    return __builtin_amdgcn_rcpf(1.0f + __builtin_amdgcn_exp2f(x * -2.8853900817779268f)) * 2.0f - 1.0f;
}
__device__ __forceinline__ unsigned f2bf(float f) {
    unsigned u = __builtin_bit_cast(unsigned, f);
    u += 0x7fffu + ((u >> 16) & 1u);   // RNE
    return u >> 16;
}
#define DPP_ADD(v, ctrl) \
    v += __builtin_bit_cast(float, __builtin_amdgcn_update_dpp(0, __builtin_bit_cast(int, v), ctrl, 0xf, 0xf, true))

__global__ __launch_bounds__(1024, 1)
void lstm_persist(const float* __restrict__ traj_in, const float* __restrict__ traj_gt,
                  const float* __restrict__ W_ih, const float* __restrict__ W_hh,
                  const float* __restrict__ b_ih, const float* __restrict__ b_hh,
                  const float* __restrict__ W_last, const float* __restrict__ b_last,
                  float* __restrict__ out, float* __restrict__ wsloss)
{
    extern __shared__ char smem[];
    const int tid  = threadIdx.x;
    const int lane = tid & 63;
    const int wave = tid >> 6;         // 0..15
    const int l15  = lane & 15;
    const int q    = (lane >> 4) & 3;  // k-quarter / row-subgroup
    const int wm   = wave >> 2;        // rows wm*16..+15
    const int wc   = wave & 3;         // h-cols wc*32..+31 (two 16-col tiles)
    const int swz  = (l15 & 7) << 4;

    // ---- stage ALL of W_hh (512 rows f32[128]) -> LDS bf16, 256B rows, swizzled
    for (int it = 0; it < 16; ++it) {
        int i = it * 1024 + tid;          // 16384 float4 items
        int n = i >> 5, q4 = i & 31;
        const float4 w = *(const float4*)(W_hh + (size_t)n * 128 + q4 * 4);
        uint2 pk = { f2bf(w.x) | (f2bf(w.y) << 16), f2bf(w.z) | (f2bf(w.w) << 16) };
        *(uint2*)(smem + W_OFF + n * 256 + ((q4 * 8) ^ ((n & 7) << 4))) = pk;
    }

    // ---- per-lane step-invariant constants
    float wih0[4][2], wih1[4][2], bias[4][2];
    #pragma unroll
    for (int g4 = 0; g4 < 4; ++g4)
        #pragma unroll
        for (int tile = 0; tile < 2; ++tile) {
            int n = g4 * 128 + wc * 32 + tile * 16 + l15;
            float2 wi = *(const float2*)(W_ih + n * 2);
            wih0[g4][tile] = wi.x; wih1[g4][tile] = wi.y;
            bias[g4][tile] = b_ih[n] + b_hh[n];
        }
    float wlA[2], wlB[2];
    #pragma unroll
    for (int tile = 0; tile < 2; ++tile) {
        int col = wc * 32 + tile * 16 + l15;
        wlA[tile] = W_last[col];
        wlB[tile] = W_last[128 + col];
    }
    const float bl0 = b_last[0], bl1 = b_last[1];
    float lossAcc = 0.f;

    for (int g = 0; g < 2; ++g) {
        const int rbase = blockIdx.x * 128 + g * 64;

        // ---- zero h; c reset
        for (int i = 0; i < 4; ++i)
            *(unsigned*)(smem + H_OFF + (tid + i * 1024) * 4) = 0u;
        float c_[2][4];
        #pragma unroll
        for (int tile = 0; tile < 2; ++tile)
            #pragma unroll
            for (int r = 0; r < 4; ++r) c_[tile][r] = 0.f;
        __syncthreads();

        for (int t = 0; t < NCELL; ++t) {
            // ---- phase 1: wave 0 fills xbuf (and emits for t>=8); all waves read a-frags
            if (wave == 0) {
                if (t < OBS) {
                    float2 x = *(const float2*)(traj_in + ((size_t)(rbase + lane) * OBS + t) * 2);
                    *(float2*)(smem + XBUF_OFF + lane * 8) = x;
                } else {
                    float o0 = bl0, o1 = bl1;
                    #pragma unroll
                    for (int ch = 0; ch < 8; ++ch) {
                        float2 s = *(const float2*)(smem + SCR_OFF + (ch * 64 + lane) * 8);
                        o0 += s.x; o1 += s.y;
                    }
                    *(float2*)(smem + XBUF_OFF + lane * 8) = make_float2(o0, o1);
                    int p = t - OBS;
                    size_t og = ((size_t)(rbase + lane) * PREDL + p) * 2;
                    float2 gt = *(const float2*)(traj_gt + og);
                    *(float2*)(out + og) = make_float2(o0, o1);
                    float d0 = o0 - gt.x, d1 = o1 - gt.y;
                    lossAcc = fmaf(d0, d0, fmaf(d1, d1, lossAcc));
                }
            }
            short8 a[4];
            #pragma unroll
            for (int ks = 0; ks < 4; ++ks)
                a[ks] = *(const short8*)(smem + H_OFF + (wm * 16 + l15) * 256 +
                                         ((ks * 64 + q * 16) ^ swz));
            __syncthreads();   // B1: xbuf ready; h reads done before overwrite

            // ---- x per row (rows q*4..q*4+3 of this wm group)
            const char* xb = smem + XBUF_OFF + (wm * 16 + q * 4) * 8;
            float4 xA = *(const float4*)(xb);        // rows q*4+0,1: (x0,x1) each
            float4 xB = *(const float4*)(xb + 16);   // rows q*4+2,3

            // ---- acc init = bias + x*W_ih (per reg), then MFMA over K=128
            f32x4 acc[2][4];
            #pragma unroll
            for (int tile = 0; tile < 2; ++tile)
                #pragma unroll
                for (int g4 = 0; g4 < 4; ++g4) {
                    f32x4 v;
                    v[0] = fmaf(xA.x, wih0[g4][tile], fmaf(xA.y, wih1[g4][tile], bias[g4][tile]));
                    v[1] = fmaf(xA.z, wih0[g4][tile], fmaf(xA.w, wih1[g4][tile], bias[g4][tile]));
                    v[2] = fmaf(xB.x, wih0[g4][tile], fmaf(xB.y, wih1[g4][tile], bias[g4][tile]));
                    v[3] = fmaf(xB.z, wih0[g4][tile], fmaf(xB.w, wih1[g4][tile], bias[g4][tile]));
                    acc[tile][g4] = v;
                }
            #pragma unroll
            for (int ks = 0; ks < 4; ++ks) {
                const int bb = (ks * 64 + q * 16) ^ swz;
                #pragma unroll
                for (int tile = 0; tile < 2; ++tile) {
                    const char* wb = smem + W_OFF + (wc * 32 + tile * 16 + l15) * 256 + bb;
                    short8 bi  = *(const short8*)(wb);
                    short8 bf_ = *(const short8*)(wb + 128 * 256);
                    short8 bg  = *(const short8*)(wb + 256 * 256);
                    short8 bo  = *(const short8*)(wb + 384 * 256);
                    acc[tile][0] = __builtin_amdgcn_mfma_f32_16x16x32_bf16(a[ks], bi,  acc[tile][0], 0, 0, 0);
                    acc[tile][1] = __builtin_amdgcn_mfma_f32_16x16x32_bf16(a[ks], bf_, acc[tile][1], 0, 0, 0);
                    acc[tile][2] = __builtin_amdgcn_mfma_f32_16x16x32_bf16(a[ks], bg,  acc[tile][2], 0, 0, 0);
                    acc[tile][3] = __builtin_amdgcn_mfma_f32_16x16x32_bf16(a[ks], bo,  acc[tile][3], 0, 0, 0);
                }
            }

            // ---- elementwise + h write + head partials
            const bool doHead = (t >= OBS - 1);
            #pragma unroll
            for (int tile = 0; tile < 2; ++tile)
                #pragma unroll
                for (int r = 0; r < 4; ++r) {
                    float iv = sigm(acc[tile][0][r]);
                    float fv = sigm(acc[tile][1][r]);
                    float gv = tanh_(acc[tile][2][r]);
                    float ov = sigm(acc[tile][3][r]);
                    float cv = fmaf(fv, c_[tile][r], iv * gv);
                    c_[tile][r] = cv;
                    float hv = ov * tanh_(cv);
                    const int rrow = q * 4 + r;              // row within 16
                    unsigned ubf = f2bf(hv);
                    unsigned nb  = (unsigned)__builtin_amdgcn_update_dpp(0, (int)ubf, 0xB1, 0xf, 0xf, true);
                    if (!(l15 & 1))
                        *(unsigned*)(smem + H_OFF + (wm * 16 + rrow) * 256 +
                                     (((wc * 32 + tile * 16 + l15) * 2) ^ ((rrow & 7) << 4))) =
                            ubf | (nb << 16);
                    if (doHead) {
                        float rl = fmaxf(hv, 0.f);
                        float v0 = rl * wlA[tile], v1 = rl * wlB[tile];
                        DPP_ADD(v0, 0x111); DPP_ADD(v0, 0x112);
                        DPP_ADD(v0, 0x114); DPP_ADD(v0, 0x118);
                        DPP_ADD(v1, 0x111); DPP_ADD(v1, 0x112);
                        DPP_ADD(v1, 0x114); DPP_ADD(v1, 0x118);
                        if (l15 == 15)
                            *(float2*)(smem + SCR_OFF +
                                       (((wc * 2 + tile) * 64) + wm * 16 + rrow) * 8) =
                                make_float2(v0, v1);
                    }
                }
            __syncthreads();   // B2: h/scr writes visible
        }

        // ---- tail: emit p = 11 = head(h_18)
        if (wave == 0) {
            float o0 = bl0, o1 = bl1;
            #pragma unroll
            for (int ch = 0; ch < 8; ++ch) {
                float2 s = *(const float2*)(smem + SCR_OFF + (ch * 64 + lane) * 8);
                o0 += s.x; o1 += s.y;
            }
            size_t og = ((size_t)(rbase + lane) * PREDL + (PREDL - 1)) * 2;
            float2 gt = *(const float2*)(traj_gt + og);
            *(float2*)(out + og) = make_float2(o0, o1);
            float d0 = o0 - gt.x, d1 = o1 - gt.y;
            lossAcc = fmaf(d0, d0, fmaf(d1, d1, lossAcc));
        }
        __syncthreads();   // protect h re-zero / scr reuse for next round
    }

    // ---- block loss partial (wave 0 only holds loss)
    if (wave == 0) {
        #pragma unroll
        for (int s = 1; s < 64; s <<= 1) lossAcc += __shfl_xor(lossAcc, s, 64);
        if (lane == 0) wsloss[blockIdx.x] = lossAcc;
    }
}

__global__ void loss_reduce(const float* __restrict__ wsloss, float* __restrict__ out,
                            int nblk, int nelem)
{
    __shared__ float sacc[4];
    int tid = threadIdx.x;   // 256
    float v = (tid < nblk) ? wsloss[tid] : 0.f;
    #pragma unroll
    for (int s = 1; s < 64; s <<= 1) v += __shfl_xor(v, s, 64);
    if ((tid & 63) == 0) sacc[tid >> 6] = v;
    __syncthreads();
    if (tid == 0) out[nelem] = (sacc[0] + sacc[1] + sacc[2] + sacc[3]) / (float)nelem;
}

extern "C" void kernel_launch(void* const* d_in, const int* in_sizes, int n_in,
                              void* d_out, int out_size, void* d_ws, size_t ws_size,
                              hipStream_t stream)
{
    const float* traj_in = (const float*)d_in[0];
    const float* traj_gt = (const float*)d_in[1];
    const float* W_ih    = (const float*)d_in[2];
    const float* W_hh    = (const float*)d_in[3];
    const float* b_ih    = (const float*)d_in[4];
    const float* b_hh    = (const float*)d_in[5];
    const float* W_last  = (const float*)d_in[6];
    const float* b_last  = (const float*)d_in[7];
    float* out = (float*)d_out;
    float* wsloss = (float*)d_ws;

    const int B      = in_sizes[0] / (OBS * 2);   // 32768
    const int blocks = B / 128;                    // 256

    lstm_persist<<<blocks, 1024, LDS_BYTES, stream>>>(traj_in, traj_gt, W_ih, W_hh,
                                                      b_ih, b_hh, W_last, b_last,
                                                      out, wsloss);
    loss_reduce<<<1, 256, 0, stream>>>(wsloss, out, blocks, out_size - 1);
}

// Round 7
// 574.093 us; speedup vs baseline: 1.0023x; 1.0023x over previous
//
#include <hip/hip_runtime.h>

#define OBS 8
#define PREDL 12
#define NCELL 19   // cell evals t=0..18; emissions head(h_7..h_18)

// LDS map (bytes)
#define W_OFF     0        // 131072: W_hh all 4 gates, 512 rows x 256B bf16, swizzled
#define H_OFF     131072   // 16384: h buffer, 64 rows x 256B, swizzled
#define SCR_OFF   147456   // 4096: head partials [8 chunks][64 rows][2] f32
#define XBUF_OFF  151552   // 512: x per row [64][2] f32
#define LDS_BYTES 152064

typedef short short8 __attribute__((ext_vector_type(8)));
typedef float f32x4  __attribute__((ext_vector_type(4)));
struct U128 { unsigned a, b, c, d; };

__device__ __forceinline__ float sigm(float x) {
    return __builtin_amdgcn_rcpf(1.0f + __builtin_amdgcn_exp2f(x * -1.4426950408889634f));
}
__device__ __forceinline__ float tanh_(float x) {
    return __builtin_amdgcn_rcpf(1.0f + __builtin_amdgcn_exp2f(x * -2.8853900817779268f)) * 2.0f - 1.0f;
}
__device__ __forceinline__ unsigned f2bf(float f) {
    unsigned u = __builtin_bit_cast(unsigned, f);
    u += 0x7fffu + ((u >> 16) & 1u);   // RNE
    return u >> 16;
}
#define DPP_ADD(v, ctrl) \
    v += __builtin_bit_cast(float, __builtin_amdgcn_update_dpp(0, __builtin_bit_cast(int, v), ctrl, 0xf, 0xf, true))

__global__ __attribute__((amdgpu_waves_per_eu(4, 4))) __launch_bounds__(1024)
void lstm_persist(const float* __restrict__ traj_in, const float* __restrict__ traj_gt,
                  const float* __restrict__ W_ih, const float* __restrict__ W_hh,
                  const float* __restrict__ b_ih, const float* __restrict__ b_hh,
                  const float* __restrict__ W_last, const float* __restrict__ b_last,
                  float* __restrict__ out, float* __restrict__ wsloss)
{
    extern __shared__ char smem[];
    const int tid  = threadIdx.x;
    const int lane = tid & 63;
    const int wave = tid >> 6;         // 0..15
    const int l15  = lane & 15;
    const int q    = (lane >> 4) & 3;  // k-quarter / row-subgroup
    const int wm   = wave >> 2;        // rows wm*16..+15
    const int wc   = wave & 3;         // h-cols wc*32..+31 (two 16-col tiles)
    const int swz  = (l15 & 7) << 4;

    // ---- stage ALL of W_hh (512 rows f32[128]) -> LDS bf16, 256B rows, swizzled
    for (int it = 0; it < 16; ++it) {
        int i = it * 1024 + tid;          // 16384 float4 items
        int n = i >> 5, q4 = i & 31;
        const float4 w = *(const float4*)(W_hh + (size_t)n * 128 + q4 * 4);
        uint2 pk = { f2bf(w.x) | (f2bf(w.y) << 16), f2bf(w.z) | (f2bf(w.w) << 16) };
        *(uint2*)(smem + W_OFF + n * 256 + ((q4 * 8) ^ ((n & 7) << 4))) = pk;
    }

    // ---- per-lane step-invariant constants
    float wih0[4][2], wih1[4][2], bias[4][2];
    #pragma unroll
    for (int g4 = 0; g4 < 4; ++g4)
        #pragma unroll
        for (int tile = 0; tile < 2; ++tile) {
            int n = g4 * 128 + wc * 32 + tile * 16 + l15;
            float2 wi = *(const float2*)(W_ih + n * 2);
            wih0[g4][tile] = wi.x; wih1[g4][tile] = wi.y;
            bias[g4][tile] = b_ih[n] + b_hh[n];
        }
    float wlA[2], wlB[2];
    #pragma unroll
    for (int tile = 0; tile < 2; ++tile) {
        int col = wc * 32 + tile * 16 + l15;
        wlA[tile] = W_last[col];
        wlB[tile] = W_last[128 + col];
    }
    const float bl0 = b_last[0], bl1 = b_last[1];
    float lossAcc = 0.f;

    for (int g = 0; g < 2; ++g) {
        const int rbase = blockIdx.x * 128 + g * 64;

        // ---- zero h; c reset
        for (int i = 0; i < 4; ++i)
            *(unsigned*)(smem + H_OFF + (tid + i * 1024) * 4) = 0u;
        float c_[2][4];
        #pragma unroll
        for (int tile = 0; tile < 2; ++tile)
            #pragma unroll
            for (int r = 0; r < 4; ++r) c_[tile][r] = 0.f;
        __syncthreads();

        for (int t = 0; t < NCELL; ++t) {
            // ---- phase 1: wave 0 fills xbuf (and emits for t>=8); all waves read a-frags
            if (wave == 0) {
                if (t < OBS) {
                    float2 x = *(const float2*)(traj_in + ((size_t)(rbase + lane) * OBS + t) * 2);
                    *(float2*)(smem + XBUF_OFF + lane * 8) = x;
                } else {
                    float o0 = bl0, o1 = bl1;
                    #pragma unroll
                    for (int ch = 0; ch < 8; ++ch) {
                        float2 s = *(const float2*)(smem + SCR_OFF + (ch * 64 + lane) * 8);
                        o0 += s.x; o1 += s.y;
                    }
                    *(float2*)(smem + XBUF_OFF + lane * 8) = make_float2(o0, o1);
                    int p = t - OBS;
                    size_t og = ((size_t)(rbase + lane) * PREDL + p) * 2;
                    float2 gt = *(const float2*)(traj_gt + og);
                    *(float2*)(out + og) = make_float2(o0, o1);
                    float d0 = o0 - gt.x, d1 = o1 - gt.y;
                    lossAcc = fmaf(d0, d0, fmaf(d1, d1, lossAcc));
                }
            }
            short8 a[4];
            #pragma unroll
            for (int ks = 0; ks < 4; ++ks)
                a[ks] = *(const short8*)(smem + H_OFF + (wm * 16 + l15) * 256 +
                                         ((ks * 64 + q * 16) ^ swz));
            __syncthreads();   // B1: xbuf ready; h reads done before overwrite

            // ---- x per row (rows q*4..q*4+3 of this wm group)
            const char* xb = smem + XBUF_OFF + (wm * 16 + q * 4) * 8;
            float4 xA = *(const float4*)(xb);        // rows q*4+0,1: (x0,x1) each
            float4 xB = *(const float4*)(xb + 16);   // rows q*4+2,3

            // ---- acc init = bias + x*W_ih (per reg), then MFMA over K=128
            f32x4 acc[2][4];
            #pragma unroll
            for (int tile = 0; tile < 2; ++tile)
                #pragma unroll
                for (int g4 = 0; g4 < 4; ++g4) {
                    f32x4 v;
                    v[0] = fmaf(xA.x, wih0[g4][tile], fmaf(xA.y, wih1[g4][tile], bias[g4][tile]));
                    v[1] = fmaf(xA.z, wih0[g4][tile], fmaf(xA.w, wih1[g4][tile], bias[g4][tile]));
                    v[2] = fmaf(xB.x, wih0[g4][tile], fmaf(xB.y, wih1[g4][tile], bias[g4][tile]));
                    v[3] = fmaf(xB.z, wih0[g4][tile], fmaf(xB.w, wih1[g4][tile], bias[g4][tile]));
                    acc[tile][g4] = v;
                }
            #pragma unroll
            for (int ks = 0; ks < 4; ++ks) {
                const int bb = (ks * 64 + q * 16) ^ swz;
                #pragma unroll
                for (int tile = 0; tile < 2; ++tile) {
                    const char* wb = smem + W_OFF + (wc * 32 + tile * 16 + l15) * 256 + bb;
                    short8 bi  = *(const short8*)(wb);
                    short8 bf_ = *(const short8*)(wb + 128 * 256);
                    short8 bg  = *(const short8*)(wb + 256 * 256);
                    short8 bo  = *(const short8*)(wb + 384 * 256);
                    acc[tile][0] = __builtin_amdgcn_mfma_f32_16x16x32_bf16(a[ks], bi,  acc[tile][0], 0, 0, 0);
                    acc[tile][1] = __builtin_amdgcn_mfma_f32_16x16x32_bf16(a[ks], bf_, acc[tile][1], 0, 0, 0);
                    acc[tile][2] = __builtin_amdgcn_mfma_f32_16x16x32_bf16(a[ks], bg,  acc[tile][2], 0, 0, 0);
                    acc[tile][3] = __builtin_amdgcn_mfma_f32_16x16x32_bf16(a[ks], bo,  acc[tile][3], 0, 0, 0);
                }
            }

            // ---- elementwise + h write + head partials
            const bool doHead = (t >= OBS - 1);
            #pragma unroll
            for (int tile = 0; tile < 2; ++tile)
                #pragma unroll
                for (int r = 0; r < 4; ++r) {
                    float iv = sigm(acc[tile][0][r]);
                    float fv = sigm(acc[tile][1][r]);
                    float gv = tanh_(acc[tile][2][r]);
                    float ov = sigm(acc[tile][3][r]);
                    float cv = fmaf(fv, c_[tile][r], iv * gv);
                    c_[tile][r] = cv;
                    float hv = ov * tanh_(cv);
                    const int rrow = q * 4 + r;              // row within 16
                    unsigned ubf = f2bf(hv);
                    unsigned nb  = (unsigned)__builtin_amdgcn_update_dpp(0, (int)ubf, 0xB1, 0xf, 0xf, true);
                    if (!(l15 & 1))
                        *(unsigned*)(smem + H_OFF + (wm * 16 + rrow) * 256 +
                                     (((wc * 32 + tile * 16 + l15) * 2) ^ ((rrow & 7) << 4))) =
                            ubf | (nb << 16);
                    if (doHead) {
                        float rl = fmaxf(hv, 0.f);
                        float v0 = rl * wlA[tile], v1 = rl * wlB[tile];
                        DPP_ADD(v0, 0x111); DPP_ADD(v0, 0x112);
                        DPP_ADD(v0, 0x114); DPP_ADD(v0, 0x118);
                        DPP_ADD(v1, 0x111); DPP_ADD(v1, 0x112);
                        DPP_ADD(v1, 0x114); DPP_ADD(v1, 0x118);
                        if (l15 == 15)
                            *(float2*)(smem + SCR_OFF +
                                       (((wc * 2 + tile) * 64) + wm * 16 + rrow) * 8) =
                                make_float2(v0, v1);
                    }
                }
            __syncthreads();   // B2: h/scr writes visible
        }

        // ---- tail: emit p = 11 = head(h_18)
        if (wave == 0) {
            float o0 = bl0, o1 = bl1;
            #pragma unroll
            for (int ch = 0; ch < 8; ++ch) {
                float2 s = *(const float2*)(smem + SCR_OFF + (ch * 64 + lane) * 8);
                o0 += s.x; o1 += s.y;
            }
            size_t og = ((size_t)(rbase + lane) * PREDL + (PREDL - 1)) * 2;
            float2 gt = *(const float2*)(traj_gt + og);
            *(float2*)(out + og) = make_float2(o0, o1);
            float d0 = o0 - gt.x, d1 = o1 - gt.y;
            lossAcc = fmaf(d0, d0, fmaf(d1, d1, lossAcc));
        }
        __syncthreads();   // protect h re-zero / scr reuse for next round
    }

    // ---- block loss partial (wave 0 only holds loss)
    if (wave == 0) {
        #pragma unroll
        for (int s = 1; s < 64; s <<= 1) lossAcc += __shfl_xor(lossAcc, s, 64);
        if (lane == 0) wsloss[blockIdx.x] = lossAcc;
    }
}

__global__ void loss_reduce(const float* __restrict__ wsloss, float* __restrict__ out,
                            int nblk, int nelem)
{
    __shared__ float sacc[4];
    int tid = threadIdx.x;   // 256
    float v = (tid < nblk) ? wsloss[tid] : 0.f;
    #pragma unroll
    for (int s = 1; s < 64; s <<= 1) v += __shfl_xor(v, s, 64);
    if ((tid & 63) == 0) sacc[tid >> 6] = v;
    __syncthreads();
    if (tid == 0) out[nelem] = (sacc[0] + sacc[1] + sacc[2] + sacc[3]) / (float)nelem;
}

extern "C" void kernel_launch(void* const* d_in, const int* in_sizes, int n_in,
                              void* d_out, int out_size, void* d_ws, size_t ws_size,
                              hipStream_t stream)
{
    const float* traj_in = (const float*)d_in[0];
    const float* traj_gt = (const float*)d_in[1];
    const float* W_ih    = (const float*)d_in[2];
    const float* W_hh    = (const float*)d_in[3];
    const float* b_ih    = (const float*)d_in[4];
    const float* b_hh    = (const float*)d_in[5];
    const float* W_last  = (const float*)d_in[6];
    const float* b_last  = (const float*)d_in[7];
    float* out = (float*)d_out;
    float* wsloss = (float*)d_ws;

    const int B      = in_sizes[0] / (OBS * 2);   // 32768
    const int blocks = B / 128;                    // 256

    lstm_persist<<<blocks, 1024, LDS_BYTES, stream>>>(traj_in, traj_gt, W_ih, W_hh,
                                                      b_ih, b_hh, W_last, b_last,
                                                      out, wsloss);
    loss_reduce<<<1, 256, 0, stream>>>(wsloss, out, blocks, out_size - 1);
}

// Round 8
// 214.174 us; speedup vs baseline: 2.6866x; 2.6805x over previous
//
#include <hip/hip_runtime.h>

#define OBS 8
#define PREDL 12
#define NCELL 19   // cell evals t=0..18

// LDS map (bytes)
#define W_OFF     0        // 98304: W_hh gates i,f,g (rows 0..383), 256B rows, swizzled
#define H_OFF     98304    // 2 x 16384: h double buffer, 64 rows x 256B, swizzled
#define EE_OFF    131072   // 8192: ext fragments [512 gcols][16B] = {wih0,wih1,bias,0..}
#define EEZ_OFF   139264   // 16: zero block for q!=0 ext reads
#define SCR_OFF   139280   // 2 x 2048: head partials [parity][64 rows][4 wc][2 f32]
#define LDS_BYTES 143376

typedef short short8 __attribute__((ext_vector_type(8)));
typedef float f32x4  __attribute__((ext_vector_type(4)));
struct U128 { unsigned a, b, c, d; };

__device__ __forceinline__ float sigm(float x) {
    return __builtin_amdgcn_rcpf(1.0f + __builtin_amdgcn_exp2f(x * -1.4426950408889634f));
}
__device__ __forceinline__ float tanh_(float x) {
    return __builtin_amdgcn_rcpf(1.0f + __builtin_amdgcn_exp2f(x * -2.8853900817779268f)) * 2.0f - 1.0f;
}
__device__ __forceinline__ unsigned f2bf(float f) {
    unsigned u = __builtin_bit_cast(unsigned, f);
    u += 0x7fffu + ((u >> 16) & 1u);   // RNE
    return u >> 16;
}
#define DPP_ADD(v, ctrl) \
    v += __builtin_bit_cast(float, __builtin_amdgcn_update_dpp(0, __builtin_bit_cast(int, v), ctrl, 0xf, 0xf, true))

// prep: W_hh gate o (rows 384..511) -> bf16 B-fragment layout in ws.
// dst[((ks*128+gcol)*4+q)*16] holds W_o[gcol][ks*32+q*8 .. +8] as bf16
__global__ void prep_o(const float* __restrict__ W_hh, char* __restrict__ wso)
{
    int idx = blockIdx.x * 256 + threadIdx.x;   // 2048
    int ks = idx >> 9, rest = idx & 511;
    int gcol = rest >> 2, q = rest & 3;
    const float* src = W_hh + (size_t)(384 + gcol) * 128 + ks * 32 + q * 8;
    float4 u = *(const float4*)src;
    float4 v = *(const float4*)(src + 4);
    U128 pk = { f2bf(u.x) | (f2bf(u.y) << 16), f2bf(u.z) | (f2bf(u.w) << 16),
                f2bf(v.x) | (f2bf(v.y) << 16), f2bf(v.z) | (f2bf(v.w) << 16) };
    *(U128*)(wso + (size_t)idx * 16) = pk;
}

__global__ __attribute__((amdgpu_waves_per_eu(4, 4))) __launch_bounds__(1024)
void lstm_persist(const float* __restrict__ traj_in, const float* __restrict__ traj_gt,
                  const float* __restrict__ W_ih, const float* __restrict__ W_hh,
                  const float* __restrict__ b_ih, const float* __restrict__ b_hh,
                  const float* __restrict__ W_last, const float* __restrict__ b_last,
                  float* __restrict__ out, const char* __restrict__ wso,
                  float* __restrict__ wsloss)
{
    extern __shared__ char smem[];
    const int tid  = threadIdx.x;
    const int lane = tid & 63;
    const int wave = tid >> 6;         // 0..15
    const int l15  = lane & 15;
    const int q    = lane >> 4;        // 0..3 (k-quarter / row-subgroup)
    const int wm   = wave >> 2;        // rows wm*16..+15
    const int wc   = wave & 3;         // h-cols wc*32..+31 (2 ntiles of 16)
    const int rbase = blockIdx.x * 64;
    const int myrow = wm * 16 + l15;   // this lane's batch row for x/emit (q==0)

    // ---- stage W_hh gates i,f,g (rows 0..383) -> LDS bf16 swizzled
    for (int it = 0; it < 12; ++it) {
        int i = it * 1024 + tid;          // 12288 float4 items
        int n = i >> 5, c4 = i & 31;
        const float4 w = *(const float4*)(W_hh + (size_t)n * 128 + c4 * 4);
        uint2 pk = { f2bf(w.x) | (f2bf(w.y) << 16), f2bf(w.z) | (f2bf(w.w) << 16) };
        *(uint2*)(smem + W_OFF + n * 256 + ((c4 * 8) ^ ((n & 7) << 4))) = pk;
    }
    // ---- stage ext fragments: row n = {Wih[n][0], Wih[n][1], bias_n, 0 x5} bf16
    if (tid < 512) {
        float2 wi = *(const float2*)(W_ih + tid * 2);
        float bsum = b_ih[tid] + b_hh[tid];
        U128 pk = { f2bf(wi.x) | (f2bf(wi.y) << 16), f2bf(bsum), 0u, 0u };
        *(U128*)(smem + EE_OFF + tid * 16) = pk;
    }
    if (tid == 512) { U128 z = {0u,0u,0u,0u}; *(U128*)(smem + EEZ_OFF) = z; }
    // ---- zero h buffer 0
    for (int i = 0; i < 4; ++i)
        *(unsigned*)(smem + H_OFF + (tid + i * 1024) * 4) = 0u;

    const float wlA0 = W_last[wc * 32 + l15];
    const float wlB0 = W_last[128 + wc * 32 + l15];
    const float wlA1 = W_last[wc * 32 + 16 + l15];
    const float wlB1 = W_last[128 + wc * 32 + 16 + l15];
    const float bl0 = b_last[0], bl1 = b_last[1];

    __syncthreads();

    float c_[8];
    #pragma unroll
    for (int i = 0; i < 8; ++i) c_[i] = 0.f;
    float lossAcc = 0.f;

    for (int t = 0; t < NCELL; ++t) {
        const int hcur = H_OFF + (t & 1) * 16384;
        const int hnxt = H_OFF + ((t & 1) ^ 1) * 16384;
        const int scrR = SCR_OFF + (t & 1) * 2048;
        const int scrW = SCR_OFF + ((t & 1) ^ 1) * 2048;

        // ---- x for this step (q==0 lanes own row myrow)
        float x0 = 0.f, x1 = 0.f;
        if (t < OBS) {
            if (q == 0) {
                float2 xx = *(const float2*)(traj_in + ((size_t)(rbase + myrow) * OBS + t) * 2);
                x0 = xx.x; x1 = xx.y;
            }
        } else {
            if (q == 0) {
                const char* sb = smem + scrR + myrow * 32;
                float4 sA = *(const float4*)(sb);
                float4 sB = *(const float4*)(sb + 16);
                x0 = ((sA.x + sA.z) + (sB.x + sB.z)) + bl0;
                x1 = ((sA.y + sA.w) + (sB.y + sB.w)) + bl1;
                if (wc == 0) {                 // emit p = t-8
                    size_t og = ((size_t)(rbase + myrow) * PREDL + (t - OBS)) * 2;
                    float2 gt = *(const float2*)(traj_gt + og);
                    *(float2*)(out + og) = make_float2(x0, x1);
                    float d0 = x0 - gt.x, d1 = x1 - gt.y;
                    lossAcc = fmaf(d0, d0, fmaf(d1, d1, lossAcc));
                }
            }
        }

        // ---- ext MFMA: acc init = x*W_ih + bias  (A = [x0,x1,1,0...], q0 lanes only)
        unsigned xpk = f2bf(x0) | (f2bf(x1) << 16);
        U128 ax = { q == 0 ? xpk : 0u, q == 0 ? 0x00003F80u : 0u, 0u, 0u };
        short8 aext = __builtin_bit_cast(short8, ax);
        f32x4 acc[2][4] = {};
        #pragma unroll
        for (int nt = 0; nt < 2; ++nt) {
            const int gb = wc * 32 + nt * 16 + l15;
            #pragma unroll
            for (int g4 = 0; g4 < 4; ++g4) {
                const char* ep = (q == 0) ? (smem + EE_OFF + (g4 * 128 + gb) * 16)
                                          : (smem + EEZ_OFF);
                short8 ee = *(const short8*)ep;
                acc[nt][g4] = __builtin_amdgcn_mfma_f32_16x16x32_bf16(aext, ee, acc[nt][g4], 0, 0, 0);
            }
        }

        // ---- main MFMAs over K=128: i,f,g from LDS, o streamed from global (L2-hot)
        #pragma unroll
        for (int ks = 0; ks < 4; ++ks) {
            const int koff = ks * 64 + q * 16;
            short8 a = *(const short8*)(smem + hcur + myrow * 256 + (koff ^ ((l15 & 7) << 4)));
            #pragma unroll
            for (int nt = 0; nt < 2; ++nt) {
                const int gb = wc * 32 + nt * 16 + l15;
                const int boff = koff ^ ((gb & 7) << 4);
                short8 bi = *(const short8*)(smem + W_OFF + gb * 256 + boff);
                short8 bf = *(const short8*)(smem + W_OFF + (128 + gb) * 256 + boff);
                short8 bg = *(const short8*)(smem + W_OFF + (256 + gb) * 256 + boff);
                short8 bo = *(const short8*)(wso + (size_t)(((ks * 128 + gb) * 4 + q)) * 16);
                acc[nt][0] = __builtin_amdgcn_mfma_f32_16x16x32_bf16(a, bi, acc[nt][0], 0, 0, 0);
                acc[nt][1] = __builtin_amdgcn_mfma_f32_16x16x32_bf16(a, bf, acc[nt][1], 0, 0, 0);
                acc[nt][2] = __builtin_amdgcn_mfma_f32_16x16x32_bf16(a, bg, acc[nt][2], 0, 0, 0);
                acc[nt][3] = __builtin_amdgcn_mfma_f32_16x16x32_bf16(a, bo, acc[nt][3], 0, 0, 0);
            }
        }

        // ---- elementwise + h write + head partials
        const bool doHead = (t >= OBS - 1);
        #pragma unroll
        for (int r = 0; r < 4; ++r) {
            const int row  = q * 4 + r;            // row within wave's 16
            const int arow = wm * 16 + row;
            const int rsw  = (row & 7) << 4;
            float v0 = 0.f, v1 = 0.f;
            #pragma unroll
            for (int nt = 0; nt < 2; ++nt) {
                float iv = sigm(acc[nt][0][r]);
                float fv = sigm(acc[nt][1][r]);
                float gv = tanh_(acc[nt][2][r]);
                float ov = sigm(acc[nt][3][r]);
                float cv = fmaf(fv, c_[nt * 4 + r], iv * gv);
                c_[nt * 4 + r] = cv;
                float hv = ov * tanh_(cv);
                *(unsigned short*)(smem + hnxt + arow * 256 +
                                   (((wc * 32 + nt * 16 + l15) * 2) ^ rsw)) =
                    (unsigned short)f2bf(hv);
                if (doHead) {
                    float rl = fmaxf(hv, 0.f);
                    v0 = fmaf(rl, nt ? wlA1 : wlA0, v0);
                    v1 = fmaf(rl, nt ? wlB1 : wlB0, v1);
                }
            }
            if (doHead) {
                DPP_ADD(v0, 0x111); DPP_ADD(v0, 0x112); DPP_ADD(v0, 0x114); DPP_ADD(v0, 0x118);
                DPP_ADD(v1, 0x111); DPP_ADD(v1, 0x112); DPP_ADD(v1, 0x114); DPP_ADD(v1, 0x118);
                if (l15 == 15)
                    *(float2*)(smem + scrW + arow * 32 + wc * 8) = make_float2(v0, v1);
            }
        }
        __syncthreads();   // one barrier/step: h[nxt], scr[W] visible for t+1
    }

    // ---- tail: emit p = 11 from scr slot (19&1)=1 (written at t=18)
    if (q == 0 && wc == 0) {
        const char* sb = smem + SCR_OFF + 2048 + myrow * 32;
        float4 sA = *(const float4*)(sb);
        float4 sB = *(const float4*)(sb + 16);
        float o0 = ((sA.x + sA.z) + (sB.x + sB.z)) + bl0;
        float o1 = ((sA.y + sA.w) + (sB.y + sB.w)) + bl1;
        size_t og = ((size_t)(rbase + myrow) * PREDL + (PREDL - 1)) * 2;
        float2 gt = *(const float2*)(traj_gt + og);
        *(float2*)(out + og) = make_float2(o0, o1);
        float d0 = o0 - gt.x, d1 = o1 - gt.y;
        lossAcc = fmaf(d0, d0, fmaf(d1, d1, lossAcc));
    }

    // ---- per-wm loss partial (wc==0 waves; only q0 lanes nonzero)
    if (wc == 0) {
        #pragma unroll
        for (int s = 1; s < 64; s <<= 1) lossAcc += __shfl_xor(lossAcc, s, 64);
        if (lane == 0) wsloss[blockIdx.x * 4 + wm] = lossAcc;
    }
}

__global__ void loss_reduce(const float* __restrict__ wsloss, float* __restrict__ out,
                            int npart, int nelem)
{
    __shared__ float sacc[4];
    int tid = threadIdx.x;   // 256
    float v = 0.f;
    for (int j = tid; j < npart; j += 256) v += wsloss[j];   // fixed order per lane
    #pragma unroll
    for (int s = 1; s < 64; s <<= 1) v += __shfl_xor(v, s, 64);
    if ((tid & 63) == 0) sacc[tid >> 6] = v;
    __syncthreads();
    if (tid == 0) out[nelem] = (sacc[0] + sacc[1] + sacc[2] + sacc[3]) / (float)nelem;
}

extern "C" void kernel_launch(void* const* d_in, const int* in_sizes, int n_in,
                              void* d_out, int out_size, void* d_ws, size_t ws_size,
                              hipStream_t stream)
{
    const float* traj_in = (const float*)d_in[0];
    const float* traj_gt = (const float*)d_in[1];
    const float* W_ih    = (const float*)d_in[2];
    const float* W_hh    = (const float*)d_in[3];
    const float* b_ih    = (const float*)d_in[4];
    const float* b_hh    = (const float*)d_in[5];
    const float* W_last  = (const float*)d_in[6];
    const float* b_last  = (const float*)d_in[7];
    float* out = (float*)d_out;
    char*  wso    = (char*)d_ws;                       // 32 KB gate-o fragments
    float* wsloss = (float*)((char*)d_ws + 32768);     // 2048 partials

    const int B      = in_sizes[0] / (OBS * 2);   // 32768
    const int blocks = B / 64;                     // 512

    prep_o<<<8, 256, 0, stream>>>(W_hh, wso);
    lstm_persist<<<blocks, 1024, LDS_BYTES, stream>>>(traj_in, traj_gt, W_ih, W_hh,
                                                      b_ih, b_hh, W_last, b_last,
                                                      out, wso, wsloss);
    loss_reduce<<<1, 256, 0, stream>>>(wsloss, out, blocks * 4, out_size - 1);
}

// Round 9
// 192.556 us; speedup vs baseline: 2.9883x; 1.1123x over previous
//
#include <hip/hip_runtime.h>

#define OBS 8
#define PREDL 12
#define NCELL 19   // cell evals t=0..18; head(h_7..h_18) emitted at t=8..19

// LDS map (bytes)
#define W_OFF     0        // 98304: W_hh gates i,f,g (rows 0..383), 256B rows, swizzled
#define H_OFF     98304    // 16384: h, 64 rows x 256B, swizzled
#define RH_OFF    114688   // 16384: relu(h), same layout
#define XBUF_OFF  131072   // 512: x [64 rows][2] f32
#define LDS_BYTES 131584

typedef short short8 __attribute__((ext_vector_type(8)));
typedef float f32x16 __attribute__((ext_vector_type(16)));
typedef float f32x4  __attribute__((ext_vector_type(4)));
struct U128 { unsigned a, b, c, d; };

__device__ __forceinline__ float sigm(float x) {
    return __builtin_amdgcn_rcpf(1.0f + __builtin_amdgcn_exp2f(x * -1.4426950408889634f));
}
__device__ __forceinline__ float tanh_(float x) {
    return __builtin_amdgcn_rcpf(1.0f + __builtin_amdgcn_exp2f(x * -2.8853900817779268f)) * 2.0f - 1.0f;
}
__device__ __forceinline__ unsigned f2bf(float f) {
    unsigned u = __builtin_bit_cast(unsigned, f);
    u += 0x7fffu + ((u >> 16) & 1u);   // RNE
    return u >> 16;
}
__device__ __forceinline__ unsigned cvtpk(float lo, float hi) {
    unsigned r;
    asm("v_cvt_pk_bf16_f32 %0, %1, %2" : "=v"(r) : "v"(lo), "v"(hi));
    return r;
}

// prep: W_hh gate o (rows 384..511) -> bf16 B-fragment layout (32x32x16) in ws.
// linear idx = ks*256 + gcol*2 + hf ; holds W_o[gcol][ks*16 + hf*8 .. +8]
__global__ void prep_o(const float* __restrict__ W_hh, char* __restrict__ wso)
{
    int idx = blockIdx.x * 256 + threadIdx.x;   // 2048
    int ks = idx >> 8, gcol = (idx >> 1) & 127, hf = idx & 1;
    const float* src = W_hh + (size_t)(384 + gcol) * 128 + ks * 16 + hf * 8;
    float4 u = *(const float4*)src;
    float4 v = *(const float4*)(src + 4);
    U128 pk = { f2bf(u.x) | (f2bf(u.y) << 16), f2bf(u.z) | (f2bf(u.w) << 16),
                f2bf(v.x) | (f2bf(v.y) << 16), f2bf(v.z) | (f2bf(v.w) << 16) };
    *(U128*)(wso + (size_t)idx * 16) = pk;
}

__global__ __attribute__((amdgpu_waves_per_eu(2, 2))) __launch_bounds__(512)
void lstm_persist(const float* __restrict__ traj_in, const float* __restrict__ traj_gt,
                  const float* __restrict__ W_ih, const float* __restrict__ W_hh,
                  const float* __restrict__ b_ih, const float* __restrict__ b_hh,
                  const float* __restrict__ W_last, const float* __restrict__ b_last,
                  float* __restrict__ out, const char* __restrict__ wso,
                  float* __restrict__ wsloss)
{
    extern __shared__ char smem[];
    const int tid  = threadIdx.x;
    const int lane = tid & 63;
    const int wave = tid >> 6;          // 0..7
    const int l31  = lane & 31;
    const int half = lane >> 5;
    const int l15  = lane & 15;
    const int q    = lane >> 4;         // 0..3 (16x16 shapes)
    const int sw   = (l31 & 7) << 4;
    const int wm   = wave >> 2;         // rows wm*32..+31
    const int wc   = wave & 3;          // gate cols wc*32..+31
    const int col0 = wc * 32;
    const int rbase = blockIdx.x * 64;
    const int myrow = wm * 32 + l31;

    // ---- stage W_hh gates i,f,g (rows 0..383) -> LDS bf16 swizzled
    for (int it = 0; it < 24; ++it) {
        int i = it * 512 + tid;            // 12288 float4 items
        int n = i >> 5, c4 = i & 31;
        const float4 w = *(const float4*)(W_hh + (size_t)n * 128 + c4 * 4);
        uint2 pk = { f2bf(w.x) | (f2bf(w.y) << 16), f2bf(w.z) | (f2bf(w.w) << 16) };
        *(uint2*)(smem + W_OFF + n * 256 + ((c4 * 8) ^ ((n & 7) << 4))) = pk;
    }
    // ---- zero h and reluh
    for (int i = 0; i < 16; ++i)
        *(unsigned*)(smem + H_OFF + (tid + i * 512) * 4) = 0u;   // covers h + reluh (32KB)

    // ---- ext B-fragments (x-weights + bias), 16 VGPRs
    short8 Ee[4];
    #pragma unroll
    for (int gg = 0; gg < 4; ++gg) {
        U128 v = { 0u, 0u, 0u, 0u };
        if (half == 0) {
            int n = gg * 128 + col0 + l31;
            float2 wi = *(const float2*)(W_ih + n * 2);
            float bsum = b_ih[n] + b_hh[n];
            v.a = f2bf(wi.x) | (f2bf(wi.y) << 16);
            v.b = f2bf(bsum);
        }
        Ee[gg] = __builtin_bit_cast(short8, v);
    }
    // ---- head B-fragments (W_last as 16x16x32 B), 16 VGPRs
    short8 Blast[4];
    #pragma unroll
    for (int ks = 0; ks < 4; ++ks) {
        U128 v = { 0u, 0u, 0u, 0u };
        if (l15 < 2) {
            const float* p = W_last + l15 * 128 + ks * 32 + q * 8;
            float4 u = *(const float4*)p;
            float4 w = *(const float4*)(p + 4);
            v.a = f2bf(u.x) | (f2bf(u.y) << 16); v.b = f2bf(u.z) | (f2bf(u.w) << 16);
            v.c = f2bf(w.x) | (f2bf(w.y) << 16); v.d = f2bf(w.z) | (f2bf(w.w) << 16);
        }
        Blast[ks] = __builtin_bit_cast(short8, v);
    }
    const float bl0 = b_last[0], bl1 = b_last[1];

    __syncthreads();

    float c_[16];
    #pragma unroll
    for (int r = 0; r < 16; ++r) c_[r] = 0.f;
    float lossAcc = 0.f;

    for (int t = 0; t <= NCELL; ++t) {
        // ======== phase 1 (pre-B1): head MFMA -> xbuf + emit; x global load; a-frags
        if (t >= OBS && !(wave & 1)) {
            const int rt = wave >> 1;            // 0..3: rows rt*16..+15
            f32x4 hd{};
            #pragma unroll
            for (int ks = 0; ks < 4; ++ks) {
                short8 ar = *(const short8*)(smem + RH_OFF + (rt * 16 + l15) * 256 +
                                             ((ks * 64 + q * 16) ^ ((l15 & 7) << 4)));
                hd = __builtin_amdgcn_mfma_f32_16x16x32_bf16(ar, Blast[ks], hd, 0, 0, 0);
            }
            if (l15 < 2) {
                const float bl = l15 ? bl1 : bl0;
                const int p = t - OBS;           // 0..11
                #pragma unroll
                for (int r = 0; r < 4; ++r) {
                    int row = rt * 16 + q * 4 + r;
                    float val = hd[r] + bl;
                    *(float*)(smem + XBUF_OFF + row * 8 + l15 * 4) = val;
                    size_t og = ((size_t)(rbase + row) * PREDL + p) * 2 + l15;
                    out[og] = val;
                    float d = val - traj_gt[og];
                    lossAcc = fmaf(d, d, lossAcc);
                }
            }
        }
        if (t == NCELL) break;                   // t==19: emission-only iteration

        float2 xx = make_float2(0.f, 0.f);
        if (half == 0 && t < OBS)
            xx = *(const float2*)(traj_in + ((size_t)(rbase + myrow) * OBS + t) * 2);

        short8 a[8];
        #pragma unroll
        for (int ks = 0; ks < 8; ++ks)
            a[ks] = *(const short8*)(smem + H_OFF + myrow * 256 + ((ks * 32 + half * 16) ^ sw));

        __syncthreads();   // B1: xbuf ready, h reads complete

        // ======== gates
        if (half == 0 && t >= OBS)
            xx = *(const float2*)(smem + XBUF_OFF + myrow * 8);
        unsigned xv = (half == 0) ? cvtpk(xx.x, xx.y) : 0u;
        U128 ax = { xv, (half == 0) ? 0x00003F80u : 0u, 0u, 0u };
        short8 aext = __builtin_bit_cast(short8, ax);

        f32x16 ac0{}, ac1{}, ac2{}, ac3{};
        ac0 = __builtin_amdgcn_mfma_f32_32x32x16_bf16(aext, Ee[0], ac0, 0, 0, 0);
        ac1 = __builtin_amdgcn_mfma_f32_32x32x16_bf16(aext, Ee[1], ac1, 0, 0, 0);
        ac2 = __builtin_amdgcn_mfma_f32_32x32x16_bf16(aext, Ee[2], ac2, 0, 0, 0);
        ac3 = __builtin_amdgcn_mfma_f32_32x32x16_bf16(aext, Ee[3], ac3, 0, 0, 0);
        #pragma unroll
        for (int ks = 0; ks < 8; ++ks) {
            const int bb = (ks * 32 + half * 16) ^ sw;
            const char* wb = smem + W_OFF + (col0 + l31) * 256 + bb;
            short8 bi  = *(const short8*)(wb);
            short8 bf_ = *(const short8*)(wb + 128 * 256);
            short8 bg  = *(const short8*)(wb + 256 * 256);
            short8 bo  = *(const short8*)(wso + (size_t)(ks * 256 + (col0 + l31) * 2 + half) * 16);
            ac0 = __builtin_amdgcn_mfma_f32_32x32x16_bf16(a[ks], bi,  ac0, 0, 0, 0);
            ac1 = __builtin_amdgcn_mfma_f32_32x32x16_bf16(a[ks], bf_, ac1, 0, 0, 0);
            ac2 = __builtin_amdgcn_mfma_f32_32x32x16_bf16(a[ks], bg,  ac2, 0, 0, 0);
            ac3 = __builtin_amdgcn_mfma_f32_32x32x16_bf16(a[ks], bo,  ac3, 0, 0, 0);
        }

        // ======== elementwise + packed h/reluh writes
        const bool doRelu = (t >= OBS - 1);
        #pragma unroll
        for (int r = 0; r < 16; ++r) {
            float iv = sigm(ac0[r]);
            float fv = sigm(ac1[r]);
            float gv = tanh_(ac2[r]);
            float ov = sigm(ac3[r]);
            float cv = fmaf(fv, c_[r], iv * gv);
            c_[r] = cv;
            float hv = ov * tanh_(cv);
            const int row  = (r & 3) + 8 * (r >> 2) + 4 * half;
            const int arow = wm * 32 + row;
            const int baddr = ((col0 + l31) * 2) ^ ((row & 7) << 4);
            float hn = __builtin_bit_cast(float,
                __builtin_amdgcn_update_dpp(0, __builtin_bit_cast(int, hv), 0xB1, 0xf, 0xf, true));
            unsigned hp = cvtpk(hv, hn);
            if (!(l31 & 1))
                *(unsigned*)(smem + H_OFF + arow * 256 + baddr) = hp;
            if (doRelu) {
                float rl = fmaxf(hv, 0.f);
                float rn = fmaxf(hn, 0.f);
                unsigned rp = cvtpk(rl, rn);
                if (!(l31 & 1))
                    *(unsigned*)(smem + RH_OFF + arow * 256 + baddr) = rp;
            }
        }
        __syncthreads();   // B2: h/reluh visible for next step
    }

    // ---- block loss partials
    #pragma unroll
    for (int s = 1; s < 64; s <<= 1) lossAcc += __shfl_xor(lossAcc, s, 64);
    if (lane == 0) wsloss[blockIdx.x * 8 + wave] = lossAcc;
}

__global__ void loss_reduce(const float* __restrict__ wsloss, float* __restrict__ out,
                            int npart, int nelem)
{
    __shared__ float sacc[4];
    int tid = threadIdx.x;   // 256
    float v = 0.f;
    for (int j = tid; j < npart; j += 256) v += wsloss[j];   // fixed order per lane
    #pragma unroll
    for (int s = 1; s < 64; s <<= 1) v += __shfl_xor(v, s, 64);
    if ((tid & 63) == 0) sacc[tid >> 6] = v;
    __syncthreads();
    if (tid == 0) out[nelem] = (sacc[0] + sacc[1] + sacc[2] + sacc[3]) / (float)nelem;
}

extern "C" void kernel_launch(void* const* d_in, const int* in_sizes, int n_in,
                              void* d_out, int out_size, void* d_ws, size_t ws_size,
                              hipStream_t stream)
{
    const float* traj_in = (const float*)d_in[0];
    const float* traj_gt = (const float*)d_in[1];
    const float* W_ih    = (const float*)d_in[2];
    const float* W_hh    = (const float*)d_in[3];
    const float* b_ih    = (const float*)d_in[4];
    const float* b_hh    = (const float*)d_in[5];
    const float* W_last  = (const float*)d_in[6];
    const float* b_last  = (const float*)d_in[7];
    float* out = (float*)d_out;
    char*  wso    = (char*)d_ws;                      // 32 KB gate-o fragments
    float* wsloss = (float*)((char*)d_ws + 32768);    // 4096 partials

    const int B      = in_sizes[0] / (OBS * 2);   // 32768
    const int blocks = B / 64;                     // 512

    prep_o<<<8, 256, 0, stream>>>(W_hh, wso);
    lstm_persist<<<blocks, 512, LDS_BYTES, stream>>>(traj_in, traj_gt, W_ih, W_hh,
                                                     b_ih, b_hh, W_last, b_last,
                                                     out, wso, wsloss);
    loss_reduce<<<1, 256, 0, stream>>>(wsloss, out, blocks * 8, out_size - 1);
}